// Round 6
// baseline (6809.612 us; speedup 1.0000x reference)
//
#include <hip/hip_runtime.h>
#include <hip/hip_bf16.h>
#include <cmath>

typedef __attribute__((ext_vector_type(8))) short bf16x8;
typedef __attribute__((ext_vector_type(4))) float f32x4;
typedef unsigned int u32;

#define DEVI __device__ __forceinline__

DEVI float sigf(float x) { return 1.0f / (1.0f + __expf(-x)); }

// async global->LDS, 16B per lane. LDS dest must be wave-uniform base (HW adds lane*16).
typedef const __attribute__((address_space(1))) u32* gas_t;
typedef __attribute__((address_space(3))) u32* las_t;
DEVI void g2l16(const void* g, void* l) {
  __builtin_amdgcn_global_load_lds((gas_t)g, (las_t)l, 16, 0, 0);
}

// ---- problem constants
#define BATCH 1024
#define CODE  2048
#define RNN   512
#define NG    2048      // 4*RNN
#define TSTEPS 128
#define K1K   2560      // CODE + RNN
#define K2K   1024      // RNN + RNN
#define K3K   512
#define NO    2176      // att cols padded: 2048 att + ang + wid + 126 pad (17 tiles of 128)

#define BUFSZ 49152     // one BK=128 K-tile stage: A 64x256B (16KB) + B 128x256B (32KB)

// ---------------------------------------------------------------------------
// prologue kernels (run every launch; d_ws is re-poisoned before each launch)
// ---------------------------------------------------------------------------

__global__ void conv_w1(const float* __restrict__ w_ih1, const float* __restrict__ w_hh1,
                        __hip_bfloat16* __restrict__ W1T) {
  int np = blockIdx.x;                       // 0..2047, gate-interleaved: np = 4u+g
  int co = (np & 3) * RNN + (np >> 2);       // original gate column
  for (int k = threadIdx.x; k < K1K; k += 256) {
    float v = (k < CODE) ? w_ih1[(size_t)k * NG + co]
                         : w_hh1[(size_t)(k - CODE) * NG + co];
    W1T[(size_t)np * K1K + k] = __float2bfloat16(v);
  }
}

__global__ void conv_w2(const float* __restrict__ w_ih2, const float* __restrict__ w_hh2,
                        __hip_bfloat16* __restrict__ W2T) {
  int np = blockIdx.x;
  int co = (np & 3) * RNN + (np >> 2);
  for (int k = threadIdx.x; k < K2K; k += 256) {
    float v = (k < RNN) ? w_ih2[(size_t)k * NG + co]
                        : w_hh2[(size_t)(k - RNN) * NG + co];
    W2T[(size_t)np * K2K + k] = __float2bfloat16(v);
  }
}

__global__ void conv_wo(const float* __restrict__ w_att, const float* __restrict__ w_ang,
                        const float* __restrict__ w_wid, __hip_bfloat16* __restrict__ WoT) {
  int n = blockIdx.x;  // 0..2175
  for (int k = threadIdx.x; k < K3K; k += 256) {
    float v = 0.f;
    if (n < CODE) v = w_att[(size_t)k * CODE + n];
    else if (n == CODE) v = w_ang[k];
    else if (n == CODE + 1) v = w_wid[k];
    WoT[(size_t)n * K3K + k] = __float2bfloat16(v);
  }
}

__global__ void conv_b(const float* b_ih1, const float* b_hh1,
                       const float* b_ih2, const float* b_hh2,
                       const float* b_att, const float* b_ang, const float* b_wid,
                       float* b1p, float* b2p, float* bo) {
  int i = blockIdx.x * 256 + threadIdx.x;
  if (i < NG) {
    int co = (i & 3) * RNN + (i >> 2);
    b1p[i] = b_ih1[co] + b_hh1[co];
    b2p[i] = b_ih2[co] + b_hh2[co];
  }
  if (i < NO) {
    float v = 0.f;
    if (i < CODE) v = b_att[i];
    else if (i == CODE) v = b_ang[0];
    else if (i == CODE + 1) v = b_wid[0];
    bo[i] = v;
  }
}

// zero h_cat(2MB)+c1(2MB)+c2(2MB) contiguous + the h1 strip of x_bf
__global__ void init_zero(char* __restrict__ zb, char* __restrict__ xb) {
  int idx = blockIdx.x * 256 + threadIdx.x;       // 262144 threads
  f32x4 z = {0.f, 0.f, 0.f, 0.f};
  for (int i = idx; i < 393216; i += 262144) *(f32x4*)(zb + (size_t)i * 16) = z;
  for (int i = idx; i < 65536; i += 262144) {
    int row = i >> 6, j = i & 63;
    *(f32x4*)(xb + (size_t)row * (K1K * 2) + CODE * 2 + (size_t)j * 16) = z;
  }
}

// idea = tanh(latent @ w_unpack + b); also x_bf[:,0:2048] = idea (att0 = 1)
__global__ void idea_kernel(const float* __restrict__ latent, const float* __restrict__ w,
                            const float* __restrict__ b,
                            __hip_bfloat16* __restrict__ idea_bf,
                            __hip_bfloat16* __restrict__ x_bf) {
  int idx = blockIdx.x * 256 + threadIdx.x;       // 2M = 1024*2048
  int bi = idx >> 11, j = idx & 2047;
  const float* lr = latent + bi * 128;
  float s = b[j];
#pragma unroll 8
  for (int k = 0; k < 128; ++k) s = fmaf(lr[k], w[(size_t)k * CODE + j], s);
  __hip_bfloat16 h = __float2bfloat16(tanhf(s));
  idea_bf[idx] = h;
  x_bf[(size_t)bi * K1K + j] = h;
}

// ---- shared GEMM inner-loop fragments --------------------------------------
// 8 waves = 2 K-half groups (kh) x (2x2) wave grid; wave tile 32x64, acc 2x4.
// LDS buffer: A [64][256B] at +0, B [128][256B] at +16384 (row stride 256B).
// Involution: LDS[r*256+q] holds global (r, q ^ ((r&7)<<4)).
// Staging: 48 1KB chunks (c<16: A rows 4c.., c>=16: B rows 4(c-16)..), 6/wave.

#define STAGE(KO, DST)                                                        \
  _Pragma("unroll") for (int j = 0; j < 6; ++j)                               \
      g2l16(gp[j] + (KO), (DST) + ldsc[j]);

#define COMPUTE(SB)                                                           \
  __builtin_amdgcn_s_setprio(1);                                              \
  _Pragma("unroll") for (int kk = 0; kk < 2; ++kk) {                          \
    bf16x8 av[2], bv[4];                                                      \
    _Pragma("unroll") for (int fm = 0; fm < 2; ++fm)                          \
        av[fm] = *(const bf16x8*)((SB) + aoff[fm][kk]);                       \
    _Pragma("unroll") for (int fn = 0; fn < 4; ++fn)                          \
        bv[fn] = *(const bf16x8*)((SB) + boff[fn][kk]);                       \
    _Pragma("unroll") for (int fm = 0; fm < 2; ++fm)                          \
      _Pragma("unroll") for (int fn = 0; fn < 4; ++fn)                        \
        acc[fm][fn] = __builtin_amdgcn_mfma_f32_16x16x32_bf16(                \
            av[fm], bv[fn], acc[fm][fn], 0, 0, 0);                            \
  }                                                                           \
  __builtin_amdgcn_s_setprio(0);

#define WAITB(N)                                                              \
  asm volatile("s_waitcnt vmcnt(" #N ")" ::: "memory");                       \
  __builtin_amdgcn_s_barrier();                                               \
  asm volatile("" ::: "memory");

// common per-thread GEMM setup (addresses + fragment offsets)
#define GEMM_SETUP(AB, BB, KBYTES)                                            \
  const int lane = tid & 63, wv = tid >> 6;                                   \
  const char* gp[6]; int ldsc[6];                                             \
  {                                                                           \
    int ccol = ((lane & 15) * 16) ^ ((lane >> 4) << 4);                       \
    _Pragma("unroll") for (int j = 0; j < 6; ++j) {                           \
      int c = wv * 6 + j;                                                     \
      int row = (c < 16) ? (m0 + c * 4 + (lane >> 4))                         \
                         : (n0 + (c - 16) * 4 + (lane >> 4));                 \
      const char* base = (c < 16) ? (AB) : (BB);                              \
      gp[j] = base + (size_t)row * (KBYTES) + (ccol ^ ((c & 1) << 6));        \
      ldsc[j] = c * 1024;                                                     \
    }                                                                         \
  }                                                                           \
  const int l16 = lane & 15, lg = lane >> 4;                                  \
  const int kh = wv >> 2, q = wv & 3, wr = q & 1, wc = q >> 1;                \
  const int xm = (l16 & 7) << 4;                                              \
  int aoff[2][2], boff[4][2];                                                 \
  _Pragma("unroll") for (int fm = 0; fm < 2; ++fm) {                          \
    int r = wr * 32 + fm * 16 + l16;                                          \
    _Pragma("unroll") for (int kk = 0; kk < 2; ++kk)                          \
      aoff[fm][kk] = r * 256 + ((kh * 128 + kk * 64 + lg * 16) ^ xm);         \
  }                                                                           \
  _Pragma("unroll") for (int fn = 0; fn < 4; ++fn) {                          \
    int r = wc * 64 + fn * 16 + l16;                                          \
    _Pragma("unroll") for (int kk = 0; kk < 2; ++kk)                          \
      boff[fn][kk] = 16384 + r * 256 + ((kh * 128 + kk * 64 + lg * 16) ^ xm); \
  }                                                                           \
  f32x4 z4 = {0.f, 0.f, 0.f, 0.f};                                            \
  f32x4 acc[2][4];                                                            \
  _Pragma("unroll") for (int a = 0; a < 2; ++a)                               \
    _Pragma("unroll") for (int b = 0; b < 4; ++b) acc[a][b] = z4;

#define GEMM_PIPELINE(NK)                                                     \
  STAGE(0, smem);                                                             \
  STAGE(256, smem + BUFSZ);                                                   \
  for (int kt = 0; kt < (NK) - 1; ++kt) {                                     \
    WAITB(6);                                                                 \
    if (kt + 2 < (NK)) {                                                      \
      char* nb = smem + ((kt + 2) % 3) * BUFSZ;                               \
      STAGE((size_t)(kt + 2) * 256, nb);                                      \
    }                                                                         \
    const char* sb = smem + (kt % 3) * BUFSZ;                                 \
    COMPUTE(sb);                                                              \
  }                                                                           \
  WAITB(0);                                                                   \
  COMPUTE(smem + (((NK) - 1) % 3) * BUFSZ);

// combine the two K-half partials in LDS (gsm stride 132 to avoid conflicts)
#define KH_COMBINE()                                                          \
  __syncthreads();                                                            \
  float* gsm = (float*)smem;                                                  \
  if (kh == 1) {                                                              \
    _Pragma("unroll") for (int fm = 0; fm < 2; ++fm)                          \
      _Pragma("unroll") for (int fn = 0; fn < 4; ++fn)                        \
        _Pragma("unroll") for (int j = 0; j < 4; ++j)                         \
          gsm[(wr * 32 + fm * 16 + lg * 4 + j) * 132 +                        \
              wc * 64 + fn * 16 + l16] = acc[fm][fn][j];                      \
  }                                                                           \
  __syncthreads();                                                            \
  if (kh == 0) {                                                              \
    _Pragma("unroll") for (int fm = 0; fm < 2; ++fm)                          \
      _Pragma("unroll") for (int fn = 0; fn < 4; ++fn)                        \
        _Pragma("unroll") for (int j = 0; j < 4; ++j)                         \
          gsm[(wr * 32 + fm * 16 + lg * 4 + j) * 132 +                        \
              wc * 64 + fn * 16 + l16] += acc[fm][fn][j];                     \
  }                                                                           \
  __syncthreads();

// ---------------------------------------------------------------------------
// Fused GEMM + LSTM cell. C = A[1024,K] @ BT[2048,K]^T, gate-interleaved N.
// BM=64, BN=128, BK=128; 512 threads = 8 waves (2 kh x 2x2), 2 waves/SIMD.
// Pipeline: 3 LDS buffers, depth 2, counted s_waitcnt vmcnt(6) + raw s_barrier.
// XCD swizzle: xcd=bid&7 owns n-tiles {2*xcd, 2*xcd+1} -> W slice L2-resident.
// ---------------------------------------------------------------------------
__global__ void __launch_bounds__(512, 2)
lstm_gemm(const char* __restrict__ Ab, const char* __restrict__ Bb,
          int K, int nk, const float* __restrict__ bias,
          float* __restrict__ c_state, __hip_bfloat16* __restrict__ h_out, int h_ld) {
  __shared__ char smem[3 * BUFSZ];  // 144KB; epilogue reuses 33KB as f32[64][132]
  const int tid = threadIdx.x;
  const int l = blockIdx.x;              // 256 blocks
  const int xcd = l & 7, bi = l >> 3;
  const int n0 = ((xcd << 1) | (bi & 1)) * 128;
  const int m0 = (bi >> 1) * 64;
  const int kb = K * 2;

  GEMM_SETUP(Ab, Bb, kb)
  GEMM_PIPELINE(nk)
  KH_COMBINE()

  // ---- cell: 64 rows x 32 units (4 gates each)
#pragma unroll
  for (int i = 0; i < 4; ++i) {
    int p = tid + i * 512;            // 2048 = 64 rows x 32 units
    int unit = p & 31, row = p >> 5;
    f32x4 g = *(const f32x4*)(gsm + row * 132 + unit * 4);
    f32x4 bb = *(const f32x4*)(bias + n0 + unit * 4);
    float ig = sigf(g.x + bb.x);
    float fg = sigf(g.y + bb.y);
    float gg = tanhf(g.z + bb.z);
    float og = sigf(g.w + bb.w);
    int grow = m0 + row, gu = (n0 >> 2) + unit;
    float cold = c_state[grow * RNN + gu];
    float cn = fg * cold + ig * gg;
    c_state[grow * RNN + gu] = cn;
    h_out[(size_t)grow * h_ld + gu] = __float2bfloat16(og * tanhf(cn));
  }
}

// ---------------------------------------------------------------------------
// K3: att = sigmoid(h2 @ WoT^T) fused with x=idea*att, heads -> out[b,t,:],
// plus state copies (blockIdx.y==0 blocks):
//   x_bf[:,2048:2560] <- h_cat[:,0:512] (h1) ;  h_cat[:,512:1024] <- h2b
// BM=64, BN=128, BK=128, grid 16x17; same pipelined core.
// ---------------------------------------------------------------------------
__global__ void __launch_bounds__(512, 2)
att_head(const char* __restrict__ Ab, const char* __restrict__ Bb,
         const float* __restrict__ bo,
         const __hip_bfloat16* __restrict__ idea_bf,
         __hip_bfloat16* __restrict__ x_bf,
         __hip_bfloat16* __restrict__ h_cat,
         const __hip_bfloat16* __restrict__ h2b,
         float* __restrict__ out, int t) {
  __shared__ char smem[3 * BUFSZ];
  const int tid = threadIdx.x;
  const int m0 = blockIdx.x * 64;
  const int n0 = blockIdx.y * 128;
  const int kb = K3K * 2;

  if (blockIdx.y == 0) {  // state copies for next step (regions disjoint from GEMM reads)
#pragma unroll
    for (int i = 0; i < 8; ++i) {
      int o = tid * 16 + i * 8192;  // 64 rows x 1024B
      int row = m0 + (o >> 10), cb = o & 1023;
      *(f32x4*)((char*)x_bf + (size_t)row * (K1K * 2) + CODE * 2 + cb) =
          *(const f32x4*)((const char*)h_cat + (size_t)row * (K2K * 2) + cb);
      *(f32x4*)((char*)h_cat + (size_t)row * (K2K * 2) + RNN * 2 + cb) =
          *(const f32x4*)((const char*)h2b + (size_t)row * (RNN * 2) + cb);
    }
  }

  GEMM_SETUP(Ab, Bb, kb)
  const int nk = K3K / 128;  // 4
  GEMM_PIPELINE(nk)
  KH_COMBINE()

  // ---- epilogue: att -> x_bf, heads -> out
#pragma unroll
  for (int i = 0; i < 16; ++i) {
    int p = tid + i * 512;            // 8192 = 64 rows x 128 cols
    int cl = p & 127, row = p >> 7;
    int col = n0 + cl;
    float v = gsm[row * 132 + cl] + bo[col];
    int grow = m0 + row;
    if (col < CODE) {
      float a = sigf(v);
      float id = __bfloat162float(idea_bf[(size_t)grow * CODE + col]);
      x_bf[(size_t)grow * K1K + col] = __float2bfloat16(id * a);
    } else if (col == CODE) {
      out[grow * (TSTEPS * 2) + t * 2] = tanhf(v);
    } else if (col == CODE + 1) {
      out[grow * (TSTEPS * 2) + t * 2 + 1] = sigf(v);
    }
  }
}

// ---------------------------------------------------------------------------
extern "C" void kernel_launch(void* const* d_in, const int* in_sizes, int n_in,
                              void* d_out, int out_size, void* d_ws, size_t ws_size,
                              hipStream_t stream) {
  const float* latent = (const float*)d_in[0];
  const float* w_unp  = (const float*)d_in[2];
  const float* b_unp  = (const float*)d_in[3];
  const float* w_ih1  = (const float*)d_in[4];
  const float* w_hh1  = (const float*)d_in[5];
  const float* b_ih1  = (const float*)d_in[6];
  const float* b_hh1  = (const float*)d_in[7];
  const float* w_ih2  = (const float*)d_in[8];
  const float* w_hh2  = (const float*)d_in[9];
  const float* b_ih2  = (const float*)d_in[10];
  const float* b_hh2  = (const float*)d_in[11];
  const float* w_att  = (const float*)d_in[12];
  const float* b_att  = (const float*)d_in[13];
  const float* w_wid  = (const float*)d_in[14];
  const float* b_wid  = (const float*)d_in[15];
  const float* w_ang  = (const float*)d_in[16];
  const float* b_ang  = (const float*)d_in[17];
  float* out = (float*)d_out;

  char* ws = (char*)d_ws;
  __hip_bfloat16* W1T  = (__hip_bfloat16*)(ws + 0);          // 2048 x 2560 bf16
  __hip_bfloat16* W2T  = (__hip_bfloat16*)(ws + 10485760);   // 2048 x 1024
  __hip_bfloat16* WoT  = (__hip_bfloat16*)(ws + 14680064);   // 2176 x 512
  float* b1p           = (float*)(ws + 16908288);            // 2048
  float* b2p           = (float*)(ws + 16916480);            // 2048
  float* bo            = (float*)(ws + 16924672);            // 2176
  __hip_bfloat16* idea = (__hip_bfloat16*)(ws + 16933376);   // 1024 x 2048
  __hip_bfloat16* x_bf = (__hip_bfloat16*)(ws + 21127680);   // 1024 x 2560  [idea*att | h1]
  __hip_bfloat16* hcat = (__hip_bfloat16*)(ws + 26370560);   // 1024 x 1024  [h1 | h2]
  float* c1            = (float*)(ws + 28467712);            // 1024 x 512
  float* c2            = (float*)(ws + 30564864);            // 1024 x 512
  __hip_bfloat16* h2b  = (__hip_bfloat16*)(ws + 32662016);   // 1024 x 512

  conv_w1<<<2048, 256, 0, stream>>>(w_ih1, w_hh1, W1T);
  conv_w2<<<2048, 256, 0, stream>>>(w_ih2, w_hh2, W2T);
  conv_wo<<<2176, 256, 0, stream>>>(w_att, w_ang, w_wid, WoT);
  conv_b<<<9, 256, 0, stream>>>(b_ih1, b_hh1, b_ih2, b_hh2, b_att, b_ang, b_wid, b1p, b2p, bo);
  init_zero<<<1024, 256, 0, stream>>>(ws + 26370560, (char*)x_bf);
  idea_kernel<<<8192, 256, 0, stream>>>(latent, w_unp, b_unp, idea, x_bf);

  for (int t = 0; t < TSTEPS; ++t) {
    lstm_gemm<<<256, 512, 0, stream>>>((const char*)x_bf, (const char*)W1T,
                                       K1K, K1K / 128, b1p, c1, hcat, 1024);
    lstm_gemm<<<256, 512, 0, stream>>>((const char*)hcat, (const char*)W2T,
                                       K2K, K2K / 128, b2p, c2, h2b, 512);
    att_head<<<dim3(16, 17), 512, 0, stream>>>((const char*)h2b, (const char*)WoT,
                                               bo, idea, x_bf, hcat, h2b, out, t);
  }
}

// Round 7
// 5381.307 us; speedup vs baseline: 1.2654x; 1.2654x over previous
//
#include <hip/hip_runtime.h>
#include <hip/hip_bf16.h>
#include <cmath>

typedef __attribute__((ext_vector_type(8))) short bf16x8;
typedef __attribute__((ext_vector_type(4))) float f32x4;
typedef unsigned int u32;

#define DEVI __device__ __forceinline__

DEVI float sigf(float x) { return 1.0f / (1.0f + __expf(-x)); }

// async global->LDS, 16B per lane. LDS dest must be wave-uniform base (HW adds lane*16).
typedef const __attribute__((address_space(1))) u32* gas_t;
typedef __attribute__((address_space(3))) u32* las_t;
DEVI void g2l16(const void* g, void* l) {
  __builtin_amdgcn_global_load_lds((gas_t)g, (las_t)l, 16, 0, 0);
}

// ---- problem constants
#define BATCH 1024
#define CODE  2048
#define RNN   512
#define NG    2048      // 4*RNN
#define TSTEPS 128
#define K1K   2560      // CODE + RNN
#define K2K   1024
#define K3K   512

#define BUFSZ 24576     // one BK=64 K-tile stage: A 8KB + B 16KB

// ---------------------------------------------------------------------------
// prologue kernels (run every launch; d_ws is re-poisoned before each launch)
// ---------------------------------------------------------------------------

__global__ void conv_w1(const float* __restrict__ w_ih1, const float* __restrict__ w_hh1,
                        __hip_bfloat16* __restrict__ W1T) {
  int np = blockIdx.x;                       // 0..2047, gate-interleaved: np = 4u+g
  int co = (np & 3) * RNN + (np >> 2);       // original gate column
  for (int k = threadIdx.x; k < K1K; k += 256) {
    float v = (k < CODE) ? w_ih1[(size_t)k * NG + co]
                         : w_hh1[(size_t)(k - CODE) * NG + co];
    W1T[(size_t)np * K1K + k] = __float2bfloat16(v);
  }
}

__global__ void conv_w2(const float* __restrict__ w_ih2, const float* __restrict__ w_hh2,
                        __hip_bfloat16* __restrict__ W2T) {
  int np = blockIdx.x;
  int co = (np & 3) * RNN + (np >> 2);
  for (int k = threadIdx.x; k < K2K; k += 256) {
    float v = (k < RNN) ? w_ih2[(size_t)k * NG + co]
                        : w_hh2[(size_t)(k - RNN) * NG + co];
    W2T[(size_t)np * K2K + k] = __float2bfloat16(v);
  }
}

// WoT[n][k], n<2048 (att only; heads handled separately)
__global__ void conv_wo(const float* __restrict__ w_att, __hip_bfloat16* __restrict__ WoT) {
  int n = blockIdx.x;  // 0..2047
  for (int k = threadIdx.x; k < K3K; k += 256)
    WoT[(size_t)n * K3K + k] = __float2bfloat16(w_att[(size_t)k * CODE + n]);
}

__global__ void conv_b(const float* b_ih1, const float* b_hh1,
                       const float* b_ih2, const float* b_hh2,
                       const float* b_att,
                       float* b1p, float* b2p, float* bo) {
  int i = blockIdx.x * 256 + threadIdx.x;
  if (i < NG) {
    int co = (i & 3) * RNN + (i >> 2);
    b1p[i] = b_ih1[co] + b_hh1[co];
    b2p[i] = b_ih2[co] + b_hh2[co];
    bo[i] = b_att[i];   // natural order, i < 2048 == NG
  }
}

// zero hbuf0(2MB)+c1(2MB)+c2(2MB) contiguous + the h1 strip of xbuf
__global__ void init_zero(char* __restrict__ zb, char* __restrict__ xb) {
  int idx = blockIdx.x * 256 + threadIdx.x;       // 262144 threads
  f32x4 z = {0.f, 0.f, 0.f, 0.f};
  for (int i = idx; i < 393216; i += 262144) *(f32x4*)(zb + (size_t)i * 16) = z;
  for (int i = idx; i < 65536; i += 262144) {
    int row = i >> 6, j = i & 63;
    *(f32x4*)(xb + (size_t)row * (K1K * 2) + CODE * 2 + (size_t)j * 16) = z;
  }
}

// idea = tanh(latent @ w_unpack + b); also xbuf[:,0:2048] = idea (att0 = 1)
__global__ void idea_kernel(const float* __restrict__ latent, const float* __restrict__ w,
                            const float* __restrict__ b,
                            __hip_bfloat16* __restrict__ idea_bf,
                            __hip_bfloat16* __restrict__ x_bf) {
  int idx = blockIdx.x * 256 + threadIdx.x;       // 2M = 1024*2048
  int bi = idx >> 11, j = idx & 2047;
  const float* lr = latent + bi * 128;
  float s = b[j];
#pragma unroll 8
  for (int k = 0; k < 128; ++k) s = fmaf(lr[k], w[(size_t)k * CODE + j], s);
  __hip_bfloat16 h = __float2bfloat16(tanhf(s));
  idea_bf[idx] = h;
  x_bf[(size_t)bi * K1K + j] = h;
}

// ---- shared GEMM inner-loop fragments (8 waves, wave tile 32x32, BK=64) ----
// LDS buffer: A[64][128B] @0, B[128][128B] @8192 (linear; involution:
// LDS[r*128+q] holds global (r, q ^ ((r&7)<<4))). 24 1KB chunks, 3/wave.

#define STAGE(KO, DST)                                                        \
  _Pragma("unroll") for (int j = 0; j < 3; ++j)                               \
      g2l16(gp[j] + (KO), (DST) + ldsc[j]);

#define COMPUTE(SB)                                                           \
  __builtin_amdgcn_s_setprio(1);                                              \
  _Pragma("unroll") for (int kk = 0; kk < 2; ++kk) {                          \
    bf16x8 av[2], bv[2];                                                      \
    _Pragma("unroll") for (int fm = 0; fm < 2; ++fm)                          \
        av[fm] = *(const bf16x8*)((SB) + aoff[fm][kk]);                       \
    _Pragma("unroll") for (int fn = 0; fn < 2; ++fn)                          \
        bv[fn] = *(const bf16x8*)((SB) + boff[fn][kk]);                       \
    _Pragma("unroll") for (int fm = 0; fm < 2; ++fm)                          \
      _Pragma("unroll") for (int fn = 0; fn < 2; ++fn)                        \
        acc[fm][fn] = __builtin_amdgcn_mfma_f32_16x16x32_bf16(                \
            av[fm], bv[fn], acc[fm][fn], 0, 0, 0);                            \
  }                                                                           \
  __builtin_amdgcn_s_setprio(0);

#define WAITB(N)                                                              \
  asm volatile("s_waitcnt vmcnt(" #N ")" ::: "memory");                       \
  __builtin_amdgcn_s_barrier();                                               \
  asm volatile("" ::: "memory");

#define GEMM_SETUP(AB, AKB, BB, BKB)                                          \
  const int lane = tid & 63, wv = tid >> 6;                                   \
  const int rl = lane >> 3;                                                   \
  const int cswz = ((lane & 7) * 16) ^ (rl << 4);                             \
  const char* gp[3]; int ldsc[3];                                             \
  _Pragma("unroll") for (int j = 0; j < 3; ++j) {                             \
    int c = wv * 3 + j;                                                       \
    int row = (c < 8) ? (m0 + c * 8 + rl) : (n0 + (c - 8) * 8 + rl);          \
    gp[j] = ((c < 8) ? (AB) : (BB)) +                                         \
            (size_t)row * ((c < 8) ? (AKB) : (BKB)) + cswz;                   \
    ldsc[j] = c * 1024;                                                       \
  }                                                                           \
  const int l16 = lane & 15, lg = lane >> 4;                                  \
  const int wr = wv & 1, wc = wv >> 1;                                        \
  const int xm = (l16 & 7) << 4;                                              \
  int aoff[2][2], boff[2][2];                                                 \
  _Pragma("unroll") for (int fm = 0; fm < 2; ++fm) {                          \
    int r = wr * 32 + fm * 16 + l16;                                          \
    _Pragma("unroll") for (int kk = 0; kk < 2; ++kk)                          \
      aoff[fm][kk] = r * 128 + ((kk * 64 + lg * 16) ^ xm);                    \
  }                                                                           \
  _Pragma("unroll") for (int fn = 0; fn < 2; ++fn) {                          \
    int r = wc * 32 + fn * 16 + l16;                                          \
    _Pragma("unroll") for (int kk = 0; kk < 2; ++kk)                          \
      boff[fn][kk] = 8192 + r * 128 + ((kk * 64 + lg * 16) ^ xm);             \
  }                                                                           \
  f32x4 z4 = {0.f, 0.f, 0.f, 0.f};                                            \
  f32x4 acc[2][2];                                                            \
  _Pragma("unroll") for (int a = 0; a < 2; ++a)                               \
    _Pragma("unroll") for (int b = 0; b < 2; ++b) acc[a][b] = z4;

#define GEMM_PIPELINE(NK)                                                     \
  STAGE(0, smem);                                                             \
  STAGE(128, smem + BUFSZ);                                                   \
  for (int kt = 0; kt < (NK) - 1; ++kt) {                                     \
    WAITB(3);                                                                 \
    if (kt + 2 < (NK)) {                                                      \
      char* nb = smem + ((kt + 2) % 3) * BUFSZ;                               \
      STAGE((size_t)(kt + 2) * 128, nb);                                      \
    }                                                                         \
    const char* sb = smem + (kt % 3) * BUFSZ;                                 \
    COMPUTE(sb);                                                              \
  }                                                                           \
  WAITB(0);                                                                   \
  COMPUTE(smem + (((NK) - 1) % 3) * BUFSZ);

// ---------------------------------------------------------------------------
// Fused GEMM + LSTM cell. C = A[1024,K] @ BT[2048,K]^T, gate-interleaved N.
// BM=64, BN=128, BK=64; 512 threads = 8 waves (2x4), wave tile 32x32.
// Writes h to hd0 (and hd1 if non-null). HEADS: per-block partial head dots.
// ---------------------------------------------------------------------------
template<bool HEADS>
__global__ void __launch_bounds__(512, 2)
lstm_gemm(const char* __restrict__ Ab, const char* __restrict__ Bb,
          int kb, int nk, const float* __restrict__ bias,
          float* __restrict__ c_state,
          __hip_bfloat16* __restrict__ hd0, int ld0,
          __hip_bfloat16* __restrict__ hd1, int ld1,
          const float* __restrict__ w_ang, const float* __restrict__ w_wid,
          float* __restrict__ partial) {
  __shared__ char smem[3 * BUFSZ];  // 72KB; epilogue reuses 32KB as f32[64][128]
  const int tid = threadIdx.x;
  const int l = blockIdx.x;              // 256 blocks, XCD-swizzled
  const int xcd = l & 7, bi = l >> 3;
  const int n0 = ((xcd << 1) | (bi & 1)) * 128;
  const int m0 = (bi >> 1) * 64;

  GEMM_SETUP(Ab, kb, Bb, kb)
  GEMM_PIPELINE(nk)

  // ---- epilogue: recombine gates in LDS, apply LSTM cell
  __syncthreads();
  float* gsm = (float*)smem;  // [64][128]
#pragma unroll
  for (int fm = 0; fm < 2; ++fm)
#pragma unroll
    for (int fn = 0; fn < 2; ++fn) {
      int col = wc * 32 + fn * 16 + l16;
#pragma unroll
      for (int j = 0; j < 4; ++j)
        gsm[(wr * 32 + fm * 16 + lg * 4 + j) * 128 + col] = acc[fm][fn][j];
    }
  __syncthreads();
#pragma unroll
  for (int i = 0; i < 4; ++i) {
    int p = tid + i * 512;            // 2048 = 64 rows x 32 units
    int unit = p & 31, row = p >> 5;
    f32x4 g = *(const f32x4*)(gsm + row * 128 + unit * 4);
    f32x4 bb = *(const f32x4*)(bias + n0 + unit * 4);
    float ig = sigf(g.x + bb.x);
    float fg = sigf(g.y + bb.y);
    float gg = tanhf(g.z + bb.z);
    float og = sigf(g.w + bb.w);
    int grow = m0 + row, gu = (n0 >> 2) + unit;
    float cold = c_state[grow * RNN + gu];
    float cn = fg * cold + ig * gg;
    c_state[grow * RNN + gu] = cn;
    float h = og * tanhf(cn);
    __hip_bfloat16 hb = __float2bfloat16(h);
    hd0[(size_t)grow * ld0 + gu] = hb;
    if (hd1) hd1[(size_t)grow * ld1 + gu] = hb;
    if (HEADS) {
      // partial head dots: 32 consecutive tids share this row
      float pa = h * w_ang[gu], pw = h * w_wid[gu];
#pragma unroll
      for (int m = 1; m < 32; m <<= 1) {
        pa += __shfl_xor(pa, m);
        pw += __shfl_xor(pw, m);
      }
      if ((tid & 31) == 0) {
        float* pp = partial + ((size_t)(n0 >> 7) * 1024 + grow) * 2;
        pp[0] = pa; pp[1] = pw;
      }
    }
  }
}

// ---------------------------------------------------------------------------
// K3: att = sigmoid(h2 @ WoT^T); xbuf[:, :2048] = idea*att.
// Also: h1 strip copy (spread over all 256 blocks, 4KB each) and, for the 16
// n0==0 blocks, finalize heads from K2's partials -> out[b,t,:].
// BM=64, BN=128, grid 256 (16x16 via XCD swizzle).
// ---------------------------------------------------------------------------
__global__ void __launch_bounds__(512, 2)
att_gemm(const char* __restrict__ Ab, int akb,      // h2 region, row stride bytes
         const char* __restrict__ Bb, int bkb,      // WoT
         const float* __restrict__ bo,
         const __hip_bfloat16* __restrict__ idea_bf,
         __hip_bfloat16* __restrict__ xbuf,
         const char* __restrict__ h1src,            // hbuf[t&1] (h1 cols 0..511)
         const float* __restrict__ partial,
         const float* __restrict__ b_ang, const float* __restrict__ b_wid,
         float* __restrict__ out, int t) {
  __shared__ char smem[3 * BUFSZ];
  const int tid = threadIdx.x;
  const int l = blockIdx.x;
  const int xcd = l & 7, bi = l >> 3;
  const int n0 = ((xcd << 1) | (bi & 1)) * 128;
  const int m0 = (bi >> 1) * 64;
  const int j16 = n0 >> 7;

  // h1 strip copy for next step's K1 input: rows m0..m0+63, 64B of cols
  if (tid < 256) {
    int row = m0 + (tid >> 2), cb = (tid & 3) * 16;
    *(f32x4*)((char*)xbuf + (size_t)row * (K1K * 2) + CODE * 2 + j16 * 64 + cb) =
        *(const f32x4*)(h1src + (size_t)row * 2048 + j16 * 64 + cb);
  }

  GEMM_SETUP(Ab, akb, Bb, bkb)
  const int nk = K3K / 64;  // 8
  GEMM_PIPELINE(nk)

  // per-lane epilogue: all cols are att
#pragma unroll
  for (int fn = 0; fn < 2; ++fn) {
    int col = n0 + wc * 32 + fn * 16 + l16;
    float bia = bo[col];
#pragma unroll
    for (int fm = 0; fm < 2; ++fm)
#pragma unroll
      for (int j = 0; j < 4; ++j) {
        int row = m0 + wr * 32 + fm * 16 + lg * 4 + j;
        float a = sigf(acc[fm][fn][j] + bia);
        float id = __bfloat162float(idea_bf[(size_t)row * CODE + col]);
        xbuf[(size_t)row * K1K + col] = __float2bfloat16(id * a);
      }
  }

  // heads finalize: 16 blocks (n0==0), 64 rows x 2 outputs each
  if (n0 == 0 && tid < 128) {
    int row = m0 + (tid >> 1), g = tid & 1;
    float s = g ? b_wid[0] : b_ang[0];
#pragma unroll
    for (int j = 0; j < 16; ++j) s += partial[((size_t)j * 1024 + row) * 2 + g];
    out[(size_t)row * (TSTEPS * 2) + t * 2 + g] = g ? sigf(s) : tanhf(s);
  }
}

// ---------------------------------------------------------------------------
extern "C" void kernel_launch(void* const* d_in, const int* in_sizes, int n_in,
                              void* d_out, int out_size, void* d_ws, size_t ws_size,
                              hipStream_t stream) {
  const float* latent = (const float*)d_in[0];
  const float* w_unp  = (const float*)d_in[2];
  const float* b_unp  = (const float*)d_in[3];
  const float* w_ih1  = (const float*)d_in[4];
  const float* w_hh1  = (const float*)d_in[5];
  const float* b_ih1  = (const float*)d_in[6];
  const float* b_hh1  = (const float*)d_in[7];
  const float* w_ih2  = (const float*)d_in[8];
  const float* w_hh2  = (const float*)d_in[9];
  const float* b_ih2  = (const float*)d_in[10];
  const float* b_hh2  = (const float*)d_in[11];
  const float* w_att  = (const float*)d_in[12];
  const float* b_att  = (const float*)d_in[13];
  const float* w_wid  = (const float*)d_in[14];
  const float* b_wid  = (const float*)d_in[15];
  const float* w_ang  = (const float*)d_in[16];
  const float* b_ang  = (const float*)d_in[17];
  float* out = (float*)d_out;

  char* ws = (char*)d_ws;
  __hip_bfloat16* W1T  = (__hip_bfloat16*)(ws + 0);          // 2048 x 2560
  __hip_bfloat16* W2T  = (__hip_bfloat16*)(ws + 10485760);   // 2048 x 1024
  __hip_bfloat16* WoT  = (__hip_bfloat16*)(ws + 14680064);   // 2048 x 512
  float* b1p           = (float*)(ws + 16777216);            // 2048
  float* b2p           = (float*)(ws + 16785408);            // 2048
  float* bo            = (float*)(ws + 16793600);            // 2048
  __hip_bfloat16* idea = (__hip_bfloat16*)(ws + 16801792);   // 1024 x 2048
  __hip_bfloat16* xbuf = (__hip_bfloat16*)(ws + 20996096);   // 1024 x 2560 [idea*att | h1]
  __hip_bfloat16* hb0  = (__hip_bfloat16*)(ws + 26238976);   // 1024 x 1024 [h1|h2]
  float* c1            = (float*)(ws + 28336128);            // 1024 x 512
  float* c2            = (float*)(ws + 30433280);            // 1024 x 512
  __hip_bfloat16* hb1  = (__hip_bfloat16*)(ws + 32530432);   // 1024 x 1024
  float* partial       = (float*)(ws + 34627584);            // 16 x 1024 x 2

  __hip_bfloat16* hbuf[2] = {hb0, hb1};

  conv_w1<<<2048, 256, 0, stream>>>(w_ih1, w_hh1, W1T);
  conv_w2<<<2048, 256, 0, stream>>>(w_ih2, w_hh2, W2T);
  conv_wo<<<2048, 256, 0, stream>>>(w_att, WoT);
  conv_b<<<8, 256, 0, stream>>>(b_ih1, b_hh1, b_ih2, b_hh2, b_att, b1p, b2p, bo);
  init_zero<<<1024, 256, 0, stream>>>(ws + 26238976, (char*)xbuf);
  idea_kernel<<<8192, 256, 0, stream>>>(latent, w_unp, b_unp, idea, xbuf);

  for (int t = 0; t < TSTEPS; ++t) {
    __hip_bfloat16* hc = hbuf[t & 1];        // [h1(t) | h2(t-1)] for K2
    __hip_bfloat16* hn = hbuf[(t + 1) & 1];  // next-step buffer
    // K1: gates1 = xbuf @ W1 ; cell -> c1, h1 -> hc[:,0:512] and xbuf is read-only here
    lstm_gemm<false><<<256, 512, 0, stream>>>(
        (const char*)xbuf, (const char*)W1T, K1K * 2, K1K / 64, b1p, c1,
        hc, 1024, (__hip_bfloat16*)nullptr, 0, nullptr, nullptr, nullptr);
    // K2: gates2 = hc @ W2 ; cell -> c2, h2 -> hn[:,512:1024]; head partials
    lstm_gemm<true><<<256, 512, 0, stream>>>(
        (const char*)hc, (const char*)W2T, K2K * 2, K2K / 64, b2p, c2,
        hn + RNN, 1024, (__hip_bfloat16*)nullptr, 0, w_ang, w_wid, partial);
    // K3: att from h2 (hn cols 512:1024); writes xbuf[:, :2048]; h1 strip copy
    // (hc cols 0:512 -> xbuf cols 2048:2560); heads finalize -> out
    att_gemm<<<256, 512, 0, stream>>>(
        (const char*)hn + 1024, 2048, (const char*)WoT, 1024,
        bo, idea, xbuf, (const char*)hc, partial, b_ang, b_wid, out, t);
  }
}